// Round 10
// baseline (1196.972 us; speedup 1.0000x reference)
//
#include <hip/hip_runtime.h>
#include <hip/hip_bf16.h>
#include <math.h>

// Problem constants
#define NB 8
#define NT 4096
#define NBT 32768      // NB*NT
#define NDIN 1024
#define ND 256
#define NH 8
#define NDK 32
#define NKC 64
#define NNS 4
#define NRK 256        // rois per batch
#define NROI 2048      // NB*NRK

#define F4Z make_float4(0.f, 0.f, 0.f, 0.f)

// ---------------------------------------------------------------------------
// K0: transpose conv weights  w[o][i][tap] -> Wt[(tap*256+i)][o]
// ---------------------------------------------------------------------------
__global__ __launch_bounds__(256) void transw_k(const float* __restrict__ w1,
    const float* __restrict__ w2, float* __restrict__ Wt1, float* __restrict__ Wt2)
{
  int i = blockIdx.x * 256 + threadIdx.x;          // < 2*196608
  const float* w = (i >= 196608) ? w2 : w1;
  float* Wt = (i >= 196608) ? Wt2 : Wt1;
  int j = (i >= 196608) ? (i - 196608) : i;
  int co = j & 255;
  int rest = j >> 8;
  int ci = rest & 255;
  int tap = rest >> 8;
  Wt[j] = w[(size_t)co * 768 + ci * 3 + tap];
}

// K0b: concat Wq|Wk|Wv -> Wqkv [256][768]
__global__ __launch_bounds__(256) void concatw_k(const float* __restrict__ Wq,
    const float* __restrict__ Wk, const float* __restrict__ Wv,
    float* __restrict__ Wqkv)
{
  int d = blockIdx.x * 256 + threadIdx.x;          // < 196608
  int r = d / 768, c = d % 768;
  int m = c >> 8, cc = c & 255;
  const float* src = (m == 0) ? Wq : (m == 1) ? Wk : Wv;
  Wqkv[d] = src[r * 256 + cc];
}

// ---------------------------------------------------------------------------
// K1: gemm1 (feature @ W_red, SELU). 128x128 tile, 8x8/thread, BK=16.
// Register-prefetch staging (issue next chunk's loads before compute; write
// to LDS after). Single LDS buffer. Component-init locals only (r4 lesson).
// ---------------------------------------------------------------------------
__global__ __launch_bounds__(256) void gemm1_k(const float* __restrict__ A,
    const float* __restrict__ W, const float* __restrict__ bias,
    float* __restrict__ C, int M, int Ka, int N)
{
  __shared__ float As[16][132];   // k-major
  __shared__ float Ws[16][128];
  int tid = threadIdx.x;
  int tx = tid & 15, ty = tid >> 4;
  int m0 = blockIdx.x * 128, n0 = blockIdx.y * 128;
  int ar = tid >> 1, acg = tid & 1;    // A staging: 128 rows x 4 cg -> 2/thread
  int wk = tid >> 5, wn = tid & 31;    // W staging: 16 k x 32 cg -> 2/thread
  float4 pa0, pa1, pw0, pw1;

#define G1LOAD(kk) do { \
    pa0 = *reinterpret_cast<const float4*>(A + (size_t)(m0 + ar) * Ka + (kk) + (acg * 2 + 0) * 4); \
    pa1 = *reinterpret_cast<const float4*>(A + (size_t)(m0 + ar) * Ka + (kk) + (acg * 2 + 1) * 4); \
    pw0 = *reinterpret_cast<const float4*>(W + (size_t)((kk) + wk) * N + n0 + wn * 4); \
    pw1 = *reinterpret_cast<const float4*>(W + (size_t)((kk) + 8 + wk) * N + n0 + wn * 4); \
  } while (0)
#define G1WRITE() do { \
    int cg0 = acg * 2, cg1 = acg * 2 + 1; \
    As[cg0 * 4 + 0][ar] = pa0.x; As[cg0 * 4 + 1][ar] = pa0.y; \
    As[cg0 * 4 + 2][ar] = pa0.z; As[cg0 * 4 + 3][ar] = pa0.w; \
    As[cg1 * 4 + 0][ar] = pa1.x; As[cg1 * 4 + 1][ar] = pa1.y; \
    As[cg1 * 4 + 2][ar] = pa1.z; As[cg1 * 4 + 3][ar] = pa1.w; \
    *reinterpret_cast<float4*>(&Ws[wk][wn * 4]) = pw0; \
    *reinterpret_cast<float4*>(&Ws[8 + wk][wn * 4]) = pw1; \
  } while (0)

  int NC = Ka >> 4;
  float acc[8][8] = {};
  G1LOAD(0);
  G1WRITE();
  __syncthreads();
  for (int c = 0; c < NC; ++c) {
    if (c + 1 < NC) G1LOAD((c + 1) * 16);
#pragma unroll
    for (int k = 0; k < 16; ++k) {
      float4 xa = *reinterpret_cast<const float4*>(&As[k][ty * 4]);
      float4 xb = *reinterpret_cast<const float4*>(&As[k][64 + ty * 4]);
      float4 wa = *reinterpret_cast<const float4*>(&Ws[k][tx * 4]);
      float4 wb = *reinterpret_cast<const float4*>(&Ws[k][64 + tx * 4]);
      float aa[8] = {xa.x, xa.y, xa.z, xa.w, xb.x, xb.y, xb.z, xb.w};
      float bb[8] = {wa.x, wa.y, wa.z, wa.w, wb.x, wb.y, wb.z, wb.w};
#pragma unroll
      for (int i = 0; i < 8; ++i)
#pragma unroll
        for (int j = 0; j < 8; ++j)
          acc[i][j] += aa[i] * bb[j];
    }
    __syncthreads();
    if (c + 1 < NC) {
      G1WRITE();
      __syncthreads();
    }
  }
#undef G1LOAD
#undef G1WRITE
#pragma unroll
  for (int i = 0; i < 8; ++i) {
    int row = m0 + ((i < 4) ? (ty * 4 + i) : (64 + ty * 4 + (i - 4)));
#pragma unroll
    for (int jh = 0; jh < 2; ++jh) {
      int col = n0 + jh * 64 + tx * 4;
      float o[4];
#pragma unroll
      for (int j = 0; j < 4; ++j) {
        float v = acc[i][jh * 4 + j] + bias[col + j];
        v = (v > 0.f) ? 1.0507009873554805f * v
                      : 1.0507009873554805f * 1.6732632423543772f * expm1f(v);
        o[j] = v;
      }
      *reinterpret_cast<float4*>(C + (size_t)row * N + col) =
          make_float4(o[0], o[1], o[2], o[3]);
    }
  }
}

// ---------------------------------------------------------------------------
// K2/K3: conv AS A K=768 GEMM (A_eff[t][tap*256+i] = in[t-1+tap][i]), with
// register-prefetch staging like gemm1. EPI=0: ReLU out; EPI=1: score fused.
// ---------------------------------------------------------------------------
template<int EPI>
__global__ __launch_bounds__(256) void conv_t(const float* __restrict__ in,
    const float* __restrict__ Wt, const float* __restrict__ bias,
    float* __restrict__ out, const float* __restrict__ Wsc,
    float* __restrict__ pscore)
{
  __shared__ float As[16][132];
  __shared__ float Ws[16][128];
  int tid = threadIdx.x;
  int tx = tid & 15, ty = tid >> 4;
  int m0 = blockIdx.x * 128, n0 = blockIdx.y * 128;
  int bstart = m0 & ~(NT - 1);
  int ar = tid >> 1, acg = tid & 1;
  int wk = tid >> 5, wn = tid & 31;
  float4 pa0, pa1, pw0, pw1;

#define CLOAD(kk) do { \
    int tap = (kk) >> 8, kd = (kk) & 255; \
    int g = m0 - 1 + tap + ar; \
    bool ok = (g >= bstart) && (g < bstart + NT); \
    pa0 = ok ? *reinterpret_cast<const float4*>(in + (size_t)g * 256 + kd + (acg * 2 + 0) * 4) : F4Z; \
    pa1 = ok ? *reinterpret_cast<const float4*>(in + (size_t)g * 256 + kd + (acg * 2 + 1) * 4) : F4Z; \
    pw0 = *reinterpret_cast<const float4*>(Wt + (size_t)((kk) + wk) * 256 + n0 + wn * 4); \
    pw1 = *reinterpret_cast<const float4*>(Wt + (size_t)((kk) + 8 + wk) * 256 + n0 + wn * 4); \
  } while (0)
#define CWRITE() do { \
    int cg0 = acg * 2, cg1 = acg * 2 + 1; \
    As[cg0 * 4 + 0][ar] = pa0.x; As[cg0 * 4 + 1][ar] = pa0.y; \
    As[cg0 * 4 + 2][ar] = pa0.z; As[cg0 * 4 + 3][ar] = pa0.w; \
    As[cg1 * 4 + 0][ar] = pa1.x; As[cg1 * 4 + 1][ar] = pa1.y; \
    As[cg1 * 4 + 2][ar] = pa1.z; As[cg1 * 4 + 3][ar] = pa1.w; \
    *reinterpret_cast<float4*>(&Ws[wk][wn * 4]) = pw0; \
    *reinterpret_cast<float4*>(&Ws[8 + wk][wn * 4]) = pw1; \
  } while (0)

  float acc[8][8] = {};
  CLOAD(0);
  CWRITE();
  __syncthreads();
  for (int c = 0; c < 48; ++c) {
    if (c + 1 < 48) CLOAD((c + 1) * 16);
#pragma unroll
    for (int k = 0; k < 16; ++k) {
      float4 xa = *reinterpret_cast<const float4*>(&As[k][ty * 4]);
      float4 xb = *reinterpret_cast<const float4*>(&As[k][64 + ty * 4]);
      float4 wa = *reinterpret_cast<const float4*>(&Ws[k][tx * 4]);
      float4 wb = *reinterpret_cast<const float4*>(&Ws[k][64 + tx * 4]);
      float aa[8] = {xa.x, xa.y, xa.z, xa.w, xb.x, xb.y, xb.z, xb.w};
      float bb[8] = {wa.x, wa.y, wa.z, wa.w, wb.x, wb.y, wb.z, wb.w};
#pragma unroll
      for (int i = 0; i < 8; ++i)
#pragma unroll
        for (int j = 0; j < 8; ++j)
          acc[i][j] += aa[i] * bb[j];
    }
    __syncthreads();
    if (c + 1 < 48) {
      CWRITE();
      __syncthreads();
    }
  }
#undef CLOAD
#undef CWRITE

  if (EPI == 0) {
#pragma unroll
    for (int i = 0; i < 8; ++i) {
      int row = m0 + ((i < 4) ? (ty * 4 + i) : (64 + ty * 4 + (i - 4)));
#pragma unroll
      for (int jh = 0; jh < 2; ++jh) {
        int col = n0 + jh * 64 + tx * 4;
        float o[4];
#pragma unroll
        for (int j = 0; j < 4; ++j)
          o[j] = fmaxf(acc[i][jh * 4 + j] + bias[col + j], 0.f);
        *reinterpret_cast<float4*>(out + (size_t)row * 256 + col) =
            make_float4(o[0], o[1], o[2], o[3]);
      }
    }
  } else {
    float p[8];
#pragma unroll
    for (int i = 0; i < 8; ++i) {
      float s = 0.f;
#pragma unroll
      for (int jh = 0; jh < 2; ++jh)
#pragma unroll
        for (int j = 0; j < 4; ++j) {
          int col = n0 + jh * 64 + tx * 4 + j;
          float v = fmaxf(acc[i][jh * 4 + j] + bias[col], 0.f);
          s += v * Wsc[col * 3];          // W_sc[col][0]
        }
      p[i] = s;
    }
#pragma unroll
    for (int off = 1; off < 16; off <<= 1)
#pragma unroll
      for (int i = 0; i < 8; ++i)
        p[i] += __shfl_xor(p[i], off, 64);
    if (tx == 0) {
#pragma unroll
      for (int i = 0; i < 8; ++i) {
        int row = m0 + ((i < 4) ? (ty * 4 + i) : (64 + ty * 4 + (i - 4)));
        pscore[(size_t)row * 2 + blockIdx.y] = p[i];
      }
    }
  }
}

// K3b: actness[g] = sigmoid(sum pscore[g][:] + b_sc0) * mask[g]
__global__ __launch_bounds__(256) void actness_k(const float* __restrict__ pscore,
    const float* __restrict__ bsc, const float* __restrict__ fmask,
    float* __restrict__ actness)
{
  int g = blockIdx.x * 256 + threadIdx.x;
  float2 pv = *reinterpret_cast<const float2*>(pscore + (size_t)g * 2);
  float z = pv.x + pv.y + bsc[0];
  actness[g] = (1.f / (1.f + expf(-z))) * fmask[g];
}

// ---------------------------------------------------------------------------
// Generic tiled fp32 GEMM (small shapes): 64x64 tile, 4x4/thread.
// ---------------------------------------------------------------------------
template<int ACT>
__global__ __launch_bounds__(256) void gemm_k(const float* __restrict__ A,
    const float* __restrict__ W, const float* __restrict__ bias,
    const float* __restrict__ resid, float* __restrict__ C,
    int M, int Ka, int N)
{
  __shared__ float As[16][66];
  __shared__ float Ws[16][68];
  int tid = threadIdx.x;
  int tx = tid & 15, ty = tid >> 4;
  int m0 = blockIdx.x * 64, n0 = blockIdx.y * 64;
  int lr = tid >> 2, lc = tid & 3;     // A-load: row, col-group
  int wr = tid >> 4, wc = tid & 15;    // W-load: row, col-group
  float4 pav, pwv;
  int NC = Ka >> 4;

#define GLOAD(kk) do { \
    pav = *reinterpret_cast<const float4*>(A + (size_t)(m0 + lr) * Ka + (kk) + lc * 4); \
    pwv = *reinterpret_cast<const float4*>(W + (size_t)((kk) + wr) * N + n0 + wc * 4); \
  } while (0)
#define GWRITE() do { \
    As[lc * 4 + 0][lr] = pav.x; As[lc * 4 + 1][lr] = pav.y; \
    As[lc * 4 + 2][lr] = pav.z; As[lc * 4 + 3][lr] = pav.w; \
    *reinterpret_cast<float4*>(&Ws[wr][wc * 4]) = pwv; \
  } while (0)

  float acc[4][4] = {};
  GLOAD(0);
  GWRITE();
  __syncthreads();
  for (int c = 0; c < NC; ++c) {
    if (c + 1 < NC) GLOAD((c + 1) * 16);
#pragma unroll
    for (int k = 0; k < 16; ++k) {
      float4 a4 = *reinterpret_cast<const float4*>(&As[k][ty * 4]);
      float4 b4 = *reinterpret_cast<const float4*>(&Ws[k][tx * 4]);
      float aa[4] = {a4.x, a4.y, a4.z, a4.w};
      float bb[4] = {b4.x, b4.y, b4.z, b4.w};
#pragma unroll
      for (int i = 0; i < 4; ++i)
#pragma unroll
        for (int j = 0; j < 4; ++j)
          acc[i][j] += aa[i] * bb[j];
    }
    __syncthreads();
    if (c + 1 < NC) {
      GWRITE();
      __syncthreads();
    }
  }
#undef GLOAD
#undef GWRITE
#pragma unroll
  for (int i = 0; i < 4; ++i) {
    int row = m0 + ty * 4 + i;
    float o[4];
#pragma unroll
    for (int j = 0; j < 4; ++j) {
      int col = n0 + tx * 4 + j;
      float v = acc[i][j];
      if (bias) v += bias[col];
      if (resid) v += resid[(size_t)row * N + col];
      if (ACT == 1) {
        v = (v > 0.f) ? 1.0507009873554805f * v
                      : 1.0507009873554805f * 1.6732632423543772f * expm1f(v);
      } else if (ACT == 2) {
        v = fmaxf(v, 0.f);
      }
      o[j] = v;
    }
    *reinterpret_cast<float4*>(C + (size_t)row * N + n0 + tx * 4) =
        make_float4(o[0], o[1], o[2], o[3]);
  }
}

// ---------------------------------------------------------------------------
// K4: per-batch exact top-64 (lax.top_k semantics: sorted desc, ties -> lower idx)
// ---------------------------------------------------------------------------
__global__ __launch_bounds__(256) void topk_k(const float* __restrict__ actness,
    float* __restrict__ topv, int* __restrict__ topi)
{
  __shared__ float wbv[4];
  __shared__ int wbi[4];
  __shared__ float gbv;
  __shared__ int gbi;
  int b = blockIdx.x;
  int tid = threadIdx.x;
  int lane = tid & 63, wvi = tid >> 6;
  float v[16];
  const float* src = actness + (size_t)b * NT + tid * 16;
#pragma unroll
  for (int j = 0; j < 16; j += 4)
    *reinterpret_cast<float4*>(&v[j]) = *reinterpret_cast<const float4*>(src + j);
  for (int it = 0; it < NKC; ++it) {
    float best = -1e30f; int bj = 0;
#pragma unroll
    for (int j = 0; j < 16; ++j)
      if (v[j] > best) { best = v[j]; bj = j; }   // first max -> lowest local idx
    int bidx = tid * 16 + bj;
#pragma unroll
    for (int off = 1; off < 64; off <<= 1) {
      float ov = __shfl_xor(best, off, 64);
      int oi = __shfl_xor(bidx, off, 64);
      if (ov > best || (ov == best && oi < bidx)) { best = ov; bidx = oi; }
    }
    if (lane == 0) { wbv[wvi] = best; wbi[wvi] = bidx; }
    __syncthreads();
    if (tid == 0) {
      float bb = wbv[0]; int bi2 = wbi[0];
#pragma unroll
      for (int w = 1; w < 4; ++w)
        if (wbv[w] > bb || (wbv[w] == bb && wbi[w] < bi2)) { bb = wbv[w]; bi2 = wbi[w]; }
      topv[b * NKC + it] = bb;
      topi[b * NKC + it] = bi2;
      gbv = bb; gbi = bi2;
    }
    __syncthreads();
    int gi = gbi;
    if ((gi >> 4) == tid) v[gi & 15] = -1e30f;
  }
}

// ---------------------------------------------------------------------------
// K5: roi generation
// ---------------------------------------------------------------------------
__global__ __launch_bounds__(256) void rois_k(const float* __restrict__ topv,
    const int* __restrict__ topi, int* __restrict__ idxb, float* __restrict__ rmask,
    float* __restrict__ rel, float* __restrict__ out_rois, float* __restrict__ out_act)
{
  int t = blockIdx.x * 256 + threadIdx.x;
  if (t >= NROI) return;
  int b = t >> 8, k = t & 255, kc = k >> 2, ns = k & 3;
  float tv = topv[b * NKC + kc];
  float c = (float)topi[b * NKC + kc];
  const float scales[4] = {16.f, 64.f, 128.f, 256.f};
  float half = scales[ns] * 0.5f;
  float s = fminf(fmaxf(c - half, 0.f), 4095.f);
  float e = fminf(fmaxf(c + half, 1.f), 4096.f);
  e = fmaxf(e, s + 1.f);
  float L = e - s;
  float ss = fminf(fmaxf(s - L * 0.25f, 0.f), 4095.f);
  float se = s + L * 0.25f;
  float es = e - L * 0.25f;
  float ee = fminf(fmaxf(e + L * 0.25f, 1.f), 4096.f);
  float st[3] = {ss, s, es};
  float en[3] = {se, e, ee};
#pragma unroll
  for (int r = 0; r < 3; ++r)
#pragma unroll
    for (int p = 0; p < 4; ++p) {
      float frac = ((float)p + 0.5f) * 0.25f;
      float fidx = floorf(st[r] + (en[r] - st[r]) * frac);
      fidx = fminf(fmaxf(fidx, 0.f), 4095.f);
      idxb[t * 12 + r * 4 + p] = (int)fidx;
    }
  rmask[t] = (tv > 0.5f) ? 1.f : 0.f;
  rel[t * 2 + 0] = s * (1.f / 4096.f);
  rel[t * 2 + 1] = e * (1.f / 4096.f);
  out_rois[t * 2 + 0] = s;
  out_rois[t * 2 + 1] = e;
  out_act[t] = tv;
}

// ---------------------------------------------------------------------------
// K6: x0 = gathered-pool GEMM + bias + pos_emb (register-prefetch staging)
// ---------------------------------------------------------------------------
__global__ __launch_bounds__(256) void pool_gemm_k(const float* __restrict__ enc,
    const int* __restrict__ idxb, const float* __restrict__ Wp,
    const float* __restrict__ bp, const float* __restrict__ rel,
    float* __restrict__ x0)
{
  __shared__ float As[16][66];
  __shared__ float Ws[16][68];
  int tid = threadIdx.x;
  int tx = tid & 15, ty = tid >> 4;
  int m0 = blockIdx.x * 64, n0 = blockIdx.y * 64;
  int lr = tid >> 2, lc = tid & 3;
  int wr = tid >> 4, wc = tid & 15;
  int roi = m0 + lr;
  int b = roi >> 8;
  float4 pav, pwv;

#define PLOAD(kk) do { \
    int slot = (kk) >> 8, kd = (kk) & 255; \
    int trow = idxb[roi * 12 + slot]; \
    pav = *reinterpret_cast<const float4*>(enc + ((size_t)(b * NT + trow)) * 256 + kd + lc * 4); \
    pwv = *reinterpret_cast<const float4*>(Wp + (size_t)((kk) + wr) * 256 + n0 + wc * 4); \
  } while (0)
#define PWRITE() do { \
    As[lc * 4 + 0][lr] = pav.x; As[lc * 4 + 1][lr] = pav.y; \
    As[lc * 4 + 2][lr] = pav.z; As[lc * 4 + 3][lr] = pav.w; \
    *reinterpret_cast<float4*>(&Ws[wr][wc * 4]) = pwv; \
  } while (0)

  float acc[4][4] = {};
  PLOAD(0);
  PWRITE();
  __syncthreads();
  for (int c = 0; c < 192; ++c) {
    if (c + 1 < 192) PLOAD((c + 1) * 16);
#pragma unroll
    for (int k = 0; k < 16; ++k) {
      float4 a4 = *reinterpret_cast<const float4*>(&As[k][ty * 4]);
      float4 b4 = *reinterpret_cast<const float4*>(&Ws[k][tx * 4]);
      float aa[4] = {a4.x, a4.y, a4.z, a4.w};
      float bb[4] = {b4.x, b4.y, b4.z, b4.w};
#pragma unroll
      for (int i = 0; i < 4; ++i)
#pragma unroll
        for (int j = 0; j < 4; ++j)
          acc[i][j] += aa[i] * bb[j];
    }
    __syncthreads();
    if (c + 1 < 192) {
      PWRITE();
      __syncthreads();
    }
  }
#undef PLOAD
#undef PWRITE
#pragma unroll
  for (int i = 0; i < 4; ++i) {
    int rr = m0 + ty * 4 + i;
    float r0 = rel[rr * 2], r1 = rel[rr * 2 + 1];
    float o[4];
#pragma unroll
    for (int j = 0; j < 4; ++j) {
      int col = n0 + tx * 4 + j;
      int rsel = col >> 7, cc = col & 127, j2 = cc & 63;
      float freq = expf(-0.14391156831212787f * (float)j2);  // ln(10000)/64
      float ang = ((rsel == 0) ? r0 : r1) * freq;
      float pe = (cc < 64) ? sinf(ang) : cosf(ang);
      o[j] = acc[i][j] + bp[col] + pe;
    }
    *reinterpret_cast<float4*>(x0 + (size_t)rr * 256 + n0 + tx * 4) =
        make_float4(o[0], o[1], o[2], o[3]);
  }
}

// ---------------------------------------------------------------------------
// K8: attention per (b,h). qkv packed [2048][768]: q=0.., k=256.., v=512..
// One-pass online softmax.
// ---------------------------------------------------------------------------
__global__ __launch_bounds__(256) void attn_k(const float* __restrict__ qkv,
    const float* __restrict__ rmask, float* __restrict__ ctx)
{
  __shared__ float ks[256][32];
  __shared__ float vs[256][32];
  int bh = blockIdx.x;
  int b = bh >> 3, h = bh & 7;
  int tid = threadIdx.x;
  size_t rowb = (size_t)b * 256;
  for (int idx = tid; idx < 2048; idx += 256) {
    int r = idx >> 3, dg = idx & 7;
    *reinterpret_cast<float4*>(&ks[r][dg * 4]) =
        *reinterpret_cast<const float4*>(qkv + (rowb + r) * 768 + 256 + h * 32 + dg * 4);
    *reinterpret_cast<float4*>(&vs[r][dg * 4]) =
        *reinterpret_cast<const float4*>(qkv + (rowb + r) * 768 + 512 + h * 32 + dg * 4);
  }
  __syncthreads();
  float qr[32];
#pragma unroll
  for (int dg = 0; dg < 8; ++dg)
    *reinterpret_cast<float4*>(&qr[dg * 4]) =
        *reinterpret_cast<const float4*>(qkv + (rowb + tid) * 768 + h * 32 + dg * 4);
  const float invs = 0.17677669529663689f;  // 1/sqrt(32)
  float m = -1e30f, l = 0.f;
  float accd[32] = {};
  for (int kk = 0; kk < 256; ++kk) {
    float s = 0.f;
#pragma unroll
    for (int d = 0; d < 32; ++d) s += qr[d] * ks[kk][d];
    s = s * invs + (1.f - rmask[b * 256 + kk]) * -1e9f;
    if (s > m) {
      float corr = expf(m - s);
      l *= corr;
#pragma unroll
      for (int d = 0; d < 32; ++d) accd[d] *= corr;
      m = s;
    }
    float p = expf(s - m);
    l += p;
#pragma unroll
    for (int d = 0; d < 32; ++d) accd[d] += p * vs[kk][d];
  }
  float inv = 1.f / l;
#pragma unroll
  for (int dg = 0; dg < 8; ++dg) {
    float4 o = make_float4(accd[dg * 4] * inv, accd[dg * 4 + 1] * inv,
                           accd[dg * 4 + 2] * inv, accd[dg * 4 + 3] * inv);
    *reinterpret_cast<float4*>(ctx + (rowb + tid) * 256 + h * 32 + dg * 4) = o;
  }
}

// ---------------------------------------------------------------------------
// K9: in-place LayerNorm over last dim (256). One wave64 per row, 4 rows/block.
// ---------------------------------------------------------------------------
__global__ __launch_bounds__(256) void ln_k(float* __restrict__ x,
    const float* __restrict__ g, const float* __restrict__ bb)
{
  int row = blockIdx.x * 4 + (threadIdx.x >> 6);
  int lane = threadIdx.x & 63;
  float* xr = x + (size_t)row * 256;
  float4 v = *reinterpret_cast<const float4*>(xr + lane * 4);
  float s = v.x + v.y + v.z + v.w;
#pragma unroll
  for (int off = 32; off > 0; off >>= 1) s += __shfl_xor(s, off, 64);
  float mean = s * 0.00390625f;
  float dx[4] = {v.x - mean, v.y - mean, v.z - mean, v.w - mean};
  float s2 = dx[0] * dx[0] + dx[1] * dx[1] + dx[2] * dx[2] + dx[3] * dx[3];
#pragma unroll
  for (int off = 32; off > 0; off >>= 1) s2 += __shfl_xor(s2, off, 64);
  float var = s2 * 0.00390625f;
  float rs = 1.f / sqrtf(var + 1e-6f);
  int c = lane * 4;
  float4 o;
  o.x = dx[0] * rs * g[c + 0] + bb[c + 0];
  o.y = dx[1] * rs * g[c + 1] + bb[c + 1];
  o.z = dx[2] * rs * g[c + 2] + bb[c + 2];
  o.w = dx[3] * rs * g[c + 3] + bb[c + 3];
  *reinterpret_cast<float4*>(xr + lane * 4) = o;
}

// ---------------------------------------------------------------------------
// K12: classifier + 2-way softmax. One wave64 per row, shuffle reduce.
// ---------------------------------------------------------------------------
__global__ __launch_bounds__(256) void cls_k(const float* __restrict__ x2,
    const float* __restrict__ Wc, const float* __restrict__ bc,
    float* __restrict__ out)
{
  int row = blockIdx.x * 4 + (threadIdx.x >> 6);
  int lane = threadIdx.x & 63;
  const float* xr = x2 + (size_t)row * 256;
  float4 xv = *reinterpret_cast<const float4*>(xr + lane * 4);
  int c = lane * 4;
  float4 w01 = *reinterpret_cast<const float4*>(Wc + c * 2);       // Wc[c..c+1][0..1]
  float4 w23 = *reinterpret_cast<const float4*>(Wc + c * 2 + 4);   // Wc[c+2..c+3][0..1]
  float l0 = xv.x * w01.x + xv.y * w01.z + xv.z * w23.x + xv.w * w23.z;
  float l1 = xv.x * w01.y + xv.y * w01.w + xv.z * w23.y + xv.w * w23.w;
#pragma unroll
  for (int off = 32; off > 0; off >>= 1) {
    l0 += __shfl_xor(l0, off, 64);
    l1 += __shfl_xor(l1, off, 64);
  }
  if (lane == 0) {
    l0 += bc[0]; l1 += bc[1];
    float mm = fmaxf(l0, l1);
    float e0 = expf(l0 - mm), e1 = expf(l1 - mm);
    float inv = 1.f / (e0 + e1);
    out[row * 2 + 0] = e0 * inv;
    out[row * 2 + 1] = e1 * inv;
  }
}

// ---------------------------------------------------------------------------
extern "C" void kernel_launch(void* const* d_in, const int* in_sizes, int n_in,
                              void* d_out, int out_size, void* d_ws, size_t ws_size,
                              hipStream_t stream) {
  (void)in_sizes; (void)n_in; (void)out_size; (void)ws_size;
  const float* feature = (const float*)d_in[0];
  const float* fmask   = (const float*)d_in[2];
  const float* W_red   = (const float*)d_in[3];
  const float* b_red   = (const float*)d_in[4];
  const float* conv1_w = (const float*)d_in[5];
  const float* conv1_b = (const float*)d_in[6];
  const float* conv2_w = (const float*)d_in[7];
  const float* conv2_b = (const float*)d_in[8];
  const float* W_sc    = (const float*)d_in[9];
  const float* b_sc    = (const float*)d_in[10];
  const float* W_pool  = (const float*)d_in[11];
  const float* b_pool  = (const float*)d_in[12];
  const float* Wq      = (const float*)d_in[13];
  const float* Wk      = (const float*)d_in[14];
  const float* Wv      = (const float*)d_in[15];
  const float* Wo      = (const float*)d_in[16];
  const float* ln1_g   = (const float*)d_in[17];
  const float* ln1_b   = (const float*)d_in[18];
  const float* W1      = (const float*)d_in[19];
  const float* b1      = (const float*)d_in[20];
  const float* W2      = (const float*)d_in[21];
  const float* b2      = (const float*)d_in[22];
  const float* ln2_g   = (const float*)d_in[23];
  const float* ln2_b   = (const float*)d_in[24];
  const float* W_cls   = (const float*)d_in[25];
  const float* b_cls   = (const float*)d_in[26];

  float* ws = (float*)d_ws;
  float* enc   = ws;                       // 8388608 floats (32768x256)
  float* h1    = ws + 8388608;             // 8388608 floats
  float* Wt1   = ws + 16777216;            // 196608
  float* Wt2   = ws + 16973824;            // 196608
  float* act   = ws + 17170432;            // 32768
  float* topv  = ws + 17203200;            // 512
  int*   topi  = (int*)(ws + 17203712);    // 512
  int*   idxb  = (int*)(ws + 17204224);    // 24576
  float* rmask = ws + 17228800;            // 2048
  float* rel   = ws + 17230848;            // 4096
  float* pscore = ws + 17234944;           // 65536 (32768x2)
  // attention-phase buffers overlay the (freed after conv2) h1 region
  float* x0   = h1;                        // 524288
  float* qkv  = h1 + 524288;               // 1572864 (2048x768)
  float* ctx  = h1 + 2097152;              // 524288
  float* x1   = h1 + 2621440;              // 524288
  float* ft   = h1 + 3145728;              // 2097152 (2048x1024)
  float* x2   = h1 + 5242880;              // 524288
  float* Wqkv = h1 + 5767168;              // 196608 (written after conv2 frees h1)

  float* orois  = (float*)d_out;           // [B,K,2] = 4096
  float* oact   = orois + 4096;            // [B,K]   = 2048
  float* oscore = orois + 6144;            // [B,K,2] = 4096

  transw_k<<<1536, 256, 0, stream>>>(conv1_w, conv2_w, Wt1, Wt2);
  gemm1_k<<<dim3(256, 2), 256, 0, stream>>>(feature, W_red, b_red, enc,
                                            NBT, NDIN, ND);
  conv_t<0><<<dim3(256, 2), 256, 0, stream>>>(enc, Wt1, conv1_b, h1, nullptr, nullptr);
  conv_t<1><<<dim3(256, 2), 256, 0, stream>>>(h1, Wt2, conv2_b, nullptr, W_sc, pscore);
  actness_k<<<128, 256, 0, stream>>>(pscore, b_sc, fmask, act);
  topk_k<<<NB, 256, 0, stream>>>(act, topv, topi);
  rois_k<<<NB, 256, 0, stream>>>(topv, topi, idxb, rmask, rel, orois, oact);
  concatw_k<<<768, 256, 0, stream>>>(Wq, Wk, Wv, Wqkv);   // h1 free after conv2
  pool_gemm_k<<<dim3(32, 4), 256, 0, stream>>>(enc, idxb, W_pool, b_pool, rel, x0);
  gemm_k<0><<<dim3(32, 12), 256, 0, stream>>>(x0, Wqkv, nullptr, nullptr, qkv,
                                              NROI, ND, 768);
  attn_k<<<NB * NH, 256, 0, stream>>>(qkv, rmask, ctx);
  gemm_k<0><<<dim3(32, 4), 256, 0, stream>>>(ctx, Wo, nullptr, x0, x1, NROI, ND, ND);
  ln_k<<<512, 256, 0, stream>>>(x1, ln1_g, ln1_b);
  gemm_k<2><<<dim3(32, 16), 256, 0, stream>>>(x1, W1, b1, nullptr, ft, NROI, ND, 1024);
  gemm_k<0><<<dim3(32, 4), 256, 0, stream>>>(ft, W2, b2, x1, x2, NROI, 1024, ND);
  ln_k<<<512, 256, 0, stream>>>(x2, ln2_g, ln2_b);
  cls_k<<<512, 256, 0, stream>>>(x2, W_cls, b_cls, oscore);
}

// Round 11
// 1063.934 us; speedup vs baseline: 1.1250x; 1.1250x over previous
//
#include <hip/hip_runtime.h>
#include <hip/hip_bf16.h>
#include <math.h>

// Problem constants
#define NB 8
#define NT 4096
#define NBT 32768      // NB*NT
#define NDIN 1024
#define ND 256
#define NH 8
#define NDK 32
#define NKC 64
#define NNS 4
#define NRK 256        // rois per batch
#define NROI 2048      // NB*NRK

#define F4Z make_float4(0.f, 0.f, 0.f, 0.f)

// ---------------------------------------------------------------------------
// K0: transpose conv weights  w[o][i][tap] -> Wt[(tap*256+i)][o]
// ---------------------------------------------------------------------------
__global__ __launch_bounds__(256) void transw_k(const float* __restrict__ w1,
    const float* __restrict__ w2, float* __restrict__ Wt1, float* __restrict__ Wt2)
{
  int i = blockIdx.x * 256 + threadIdx.x;          // < 2*196608
  const float* w = (i >= 196608) ? w2 : w1;
  float* Wt = (i >= 196608) ? Wt2 : Wt1;
  int j = (i >= 196608) ? (i - 196608) : i;
  int co = j & 255;
  int rest = j >> 8;
  int ci = rest & 255;
  int tap = rest >> 8;
  Wt[j] = w[(size_t)co * 768 + ci * 3 + tap];
}

// K0b: concat Wq|Wk|Wv -> Wqkv [256][768]
__global__ __launch_bounds__(256) void concatw_k(const float* __restrict__ Wq,
    const float* __restrict__ Wk, const float* __restrict__ Wv,
    float* __restrict__ Wqkv)
{
  int d = blockIdx.x * 256 + threadIdx.x;          // < 196608
  int r = d / 768, c = d % 768;
  int m = c >> 8, cc = c & 255;
  const float* src = (m == 0) ? Wq : (m == 1) ? Wk : Wv;
  Wqkv[d] = src[r * 256 + cc];
}

// ---------------------------------------------------------------------------
// K1: gemm1 (feature @ W_red, SELU). 128x128 tile, 8x8/thread, BK=16.
// Single-buffer, uncapped (round-9 proven: VGPR 72, no spill).
// ---------------------------------------------------------------------------
__global__ __launch_bounds__(256) void gemm1_k(const float* __restrict__ A,
    const float* __restrict__ W, const float* __restrict__ bias,
    float* __restrict__ C, int M, int Ka, int N)
{
  __shared__ float As[16][132];   // k-major
  __shared__ float Ws[16][128];
  int tid = threadIdx.x;
  int tx = tid & 15, ty = tid >> 4;
  int m0 = blockIdx.x * 128, n0 = blockIdx.y * 128;
  int ar = tid >> 1, acg = tid & 1;    // A staging: 128 rows x 4 cg -> 2/thread
  int wk = tid >> 5, wn = tid & 31;    // W staging: 16 k x 32 cg -> 2/thread
  float acc[8][8] = {};
  for (int kk = 0; kk < Ka; kk += 16) {
#pragma unroll
    for (int p = 0; p < 2; ++p) {
      int cg = acg * 2 + p;
      float4 av = *reinterpret_cast<const float4*>(A + (size_t)(m0 + ar) * Ka + kk + cg * 4);
      As[cg * 4 + 0][ar] = av.x;
      As[cg * 4 + 1][ar] = av.y;
      As[cg * 4 + 2][ar] = av.z;
      As[cg * 4 + 3][ar] = av.w;
    }
#pragma unroll
    for (int p = 0; p < 2; ++p) {
      int k = wk + p * 8;
      *reinterpret_cast<float4*>(&Ws[k][wn * 4]) =
          *reinterpret_cast<const float4*>(W + (size_t)(kk + k) * N + n0 + wn * 4);
    }
    __syncthreads();
#pragma unroll
    for (int k = 0; k < 16; ++k) {
      float4 xa = *reinterpret_cast<const float4*>(&As[k][ty * 4]);
      float4 xb = *reinterpret_cast<const float4*>(&As[k][64 + ty * 4]);
      float4 wa = *reinterpret_cast<const float4*>(&Ws[k][tx * 4]);
      float4 wb = *reinterpret_cast<const float4*>(&Ws[k][64 + tx * 4]);
      float aa[8] = {xa.x, xa.y, xa.z, xa.w, xb.x, xb.y, xb.z, xb.w};
      float bb[8] = {wa.x, wa.y, wa.z, wa.w, wb.x, wb.y, wb.z, wb.w};
#pragma unroll
      for (int i = 0; i < 8; ++i)
#pragma unroll
        for (int j = 0; j < 8; ++j)
          acc[i][j] += aa[i] * bb[j];
    }
    __syncthreads();
  }
#pragma unroll
  for (int i = 0; i < 8; ++i) {
    int row = m0 + ((i < 4) ? (ty * 4 + i) : (64 + ty * 4 + (i - 4)));
#pragma unroll
    for (int jh = 0; jh < 2; ++jh) {
      int col = n0 + jh * 64 + tx * 4;
      float o[4];
#pragma unroll
      for (int j = 0; j < 4; ++j) {
        float v = acc[i][jh * 4 + j] + bias[col + j];
        v = (v > 0.f) ? 1.0507009873554805f * v
                      : 1.0507009873554805f * 1.6732632423543772f * expm1f(v);
        o[j] = v;
      }
      *reinterpret_cast<float4*>(C + (size_t)row * N + col) =
          make_float4(o[0], o[1], o[2], o[3]);
    }
  }
}

// ---------------------------------------------------------------------------
// K2/K3: conv AS A K=768 GEMM (A_eff[t][tap*256+i] = in[t-1+tap][i]).
// Round-9 proven single-buffer 8x8. EPI=0: ReLU out; EPI=1: score fused.
// ---------------------------------------------------------------------------
template<int EPI>
__global__ __launch_bounds__(256) void conv_t(const float* __restrict__ in,
    const float* __restrict__ Wt, const float* __restrict__ bias,
    float* __restrict__ out, const float* __restrict__ Wsc,
    float* __restrict__ pscore)
{
  __shared__ float As[16][132];
  __shared__ float Ws[16][128];
  int tid = threadIdx.x;
  int tx = tid & 15, ty = tid >> 4;
  int m0 = blockIdx.x * 128, n0 = blockIdx.y * 128;
  int bstart = m0 & ~(NT - 1);
  int ar = tid >> 1, acg = tid & 1;
  int wk = tid >> 5, wn = tid & 31;
  float acc[8][8] = {};
  for (int kk = 0; kk < 768; kk += 16) {
    int tap = kk >> 8, kd = kk & 255;
    int g = m0 - 1 + tap + ar;
    bool ok = (g >= bstart) && (g < bstart + NT);
#pragma unroll
    for (int p = 0; p < 2; ++p) {
      int cg = acg * 2 + p;
      float4 av = ok ? *reinterpret_cast<const float4*>(in + (size_t)g * 256 + kd + cg * 4)
                     : F4Z;
      As[cg * 4 + 0][ar] = av.x;
      As[cg * 4 + 1][ar] = av.y;
      As[cg * 4 + 2][ar] = av.z;
      As[cg * 4 + 3][ar] = av.w;
    }
#pragma unroll
    for (int p = 0; p < 2; ++p) {
      int k = wk + p * 8;
      *reinterpret_cast<float4*>(&Ws[k][wn * 4]) =
          *reinterpret_cast<const float4*>(Wt + (size_t)(kk + k) * 256 + n0 + wn * 4);
    }
    __syncthreads();
#pragma unroll
    for (int k = 0; k < 16; ++k) {
      float4 xa = *reinterpret_cast<const float4*>(&As[k][ty * 4]);
      float4 xb = *reinterpret_cast<const float4*>(&As[k][64 + ty * 4]);
      float4 wa = *reinterpret_cast<const float4*>(&Ws[k][tx * 4]);
      float4 wb = *reinterpret_cast<const float4*>(&Ws[k][64 + tx * 4]);
      float aa[8] = {xa.x, xa.y, xa.z, xa.w, xb.x, xb.y, xb.z, xb.w};
      float bb[8] = {wa.x, wa.y, wa.z, wa.w, wb.x, wb.y, wb.z, wb.w};
#pragma unroll
      for (int i = 0; i < 8; ++i)
#pragma unroll
        for (int j = 0; j < 8; ++j)
          acc[i][j] += aa[i] * bb[j];
    }
    __syncthreads();
  }

  if (EPI == 0) {
#pragma unroll
    for (int i = 0; i < 8; ++i) {
      int row = m0 + ((i < 4) ? (ty * 4 + i) : (64 + ty * 4 + (i - 4)));
#pragma unroll
      for (int jh = 0; jh < 2; ++jh) {
        int col = n0 + jh * 64 + tx * 4;
        float o[4];
#pragma unroll
        for (int j = 0; j < 4; ++j)
          o[j] = fmaxf(acc[i][jh * 4 + j] + bias[col + j], 0.f);
        *reinterpret_cast<float4*>(out + (size_t)row * 256 + col) =
            make_float4(o[0], o[1], o[2], o[3]);
      }
    }
  } else {
    float p[8];
#pragma unroll
    for (int i = 0; i < 8; ++i) {
      float s = 0.f;
#pragma unroll
      for (int jh = 0; jh < 2; ++jh)
#pragma unroll
        for (int j = 0; j < 4; ++j) {
          int col = n0 + jh * 64 + tx * 4 + j;
          float v = fmaxf(acc[i][jh * 4 + j] + bias[col], 0.f);
          s += v * Wsc[col * 3];          // W_sc[col][0]
        }
      p[i] = s;
    }
#pragma unroll
    for (int off = 1; off < 16; off <<= 1)
#pragma unroll
      for (int i = 0; i < 8; ++i)
        p[i] += __shfl_xor(p[i], off, 64);
    if (tx == 0) {
#pragma unroll
      for (int i = 0; i < 8; ++i) {
        int row = m0 + ((i < 4) ? (ty * 4 + i) : (64 + ty * 4 + (i - 4)));
        pscore[(size_t)row * 2 + blockIdx.y] = p[i];
      }
    }
  }
}

// K3b: actness[g] = sigmoid(sum pscore[g][:] + b_sc0) * mask[g]
__global__ __launch_bounds__(256) void actness_k(const float* __restrict__ pscore,
    const float* __restrict__ bsc, const float* __restrict__ fmask,
    float* __restrict__ actness)
{
  int g = blockIdx.x * 256 + threadIdx.x;
  float2 pv = *reinterpret_cast<const float2*>(pscore + (size_t)g * 2);
  float z = pv.x + pv.y + bsc[0];
  actness[g] = (1.f / (1.f + expf(-z))) * fmask[g];
}

// ---------------------------------------------------------------------------
// Generic tiled fp32 GEMM (small shapes): 64x64 tile, 4x4/thread (r9 plain).
// ---------------------------------------------------------------------------
template<int ACT>
__global__ __launch_bounds__(256) void gemm_k(const float* __restrict__ A,
    const float* __restrict__ W, const float* __restrict__ bias,
    const float* __restrict__ resid, float* __restrict__ C,
    int M, int Ka, int N)
{
  __shared__ float As[16][66];
  __shared__ float Ws[16][68];
  int tid = threadIdx.x;
  int tx = tid & 15, ty = tid >> 4;
  int m0 = blockIdx.x * 64, n0 = blockIdx.y * 64;
  int lr = tid >> 2, lc = tid & 3;     // A-load: row, col-group
  int wr = tid >> 4, wc = tid & 15;    // W-load: row, col-group
  float acc[4][4] = {};
  for (int kk = 0; kk < Ka; kk += 16) {
    float4 av = *reinterpret_cast<const float4*>(A + (size_t)(m0 + lr) * Ka + kk + lc * 4);
    As[lc * 4 + 0][lr] = av.x;
    As[lc * 4 + 1][lr] = av.y;
    As[lc * 4 + 2][lr] = av.z;
    As[lc * 4 + 3][lr] = av.w;
    float4 wv = *reinterpret_cast<const float4*>(W + (size_t)(kk + wr) * N + n0 + wc * 4);
    *reinterpret_cast<float4*>(&Ws[wr][wc * 4]) = wv;
    __syncthreads();
#pragma unroll
    for (int k = 0; k < 16; ++k) {
      float4 a4 = *reinterpret_cast<const float4*>(&As[k][ty * 4]);
      float4 b4 = *reinterpret_cast<const float4*>(&Ws[k][tx * 4]);
      float aa[4] = {a4.x, a4.y, a4.z, a4.w};
      float bb[4] = {b4.x, b4.y, b4.z, b4.w};
#pragma unroll
      for (int i = 0; i < 4; ++i)
#pragma unroll
        for (int j = 0; j < 4; ++j)
          acc[i][j] += aa[i] * bb[j];
    }
    __syncthreads();
  }
#pragma unroll
  for (int i = 0; i < 4; ++i) {
    int row = m0 + ty * 4 + i;
    float o[4];
#pragma unroll
    for (int j = 0; j < 4; ++j) {
      int col = n0 + tx * 4 + j;
      float v = acc[i][j];
      if (bias) v += bias[col];
      if (resid) v += resid[(size_t)row * N + col];
      if (ACT == 1) {
        v = (v > 0.f) ? 1.0507009873554805f * v
                      : 1.0507009873554805f * 1.6732632423543772f * expm1f(v);
      } else if (ACT == 2) {
        v = fmaxf(v, 0.f);
      }
      o[j] = v;
    }
    *reinterpret_cast<float4*>(C + (size_t)row * N + n0 + tx * 4) =
        make_float4(o[0], o[1], o[2], o[3]);
  }
}

// ---------------------------------------------------------------------------
// K4: per-batch exact top-64 (lax.top_k semantics: sorted desc, ties -> lower idx)
// ---------------------------------------------------------------------------
__global__ __launch_bounds__(256) void topk_k(const float* __restrict__ actness,
    float* __restrict__ topv, int* __restrict__ topi)
{
  __shared__ float wbv[4];
  __shared__ int wbi[4];
  __shared__ float gbv;
  __shared__ int gbi;
  int b = blockIdx.x;
  int tid = threadIdx.x;
  int lane = tid & 63, wvi = tid >> 6;
  float v[16];
  const float* src = actness + (size_t)b * NT + tid * 16;
#pragma unroll
  for (int j = 0; j < 16; j += 4)
    *reinterpret_cast<float4*>(&v[j]) = *reinterpret_cast<const float4*>(src + j);
  for (int it = 0; it < NKC; ++it) {
    float best = -1e30f; int bj = 0;
#pragma unroll
    for (int j = 0; j < 16; ++j)
      if (v[j] > best) { best = v[j]; bj = j; }   // first max -> lowest local idx
    int bidx = tid * 16 + bj;
#pragma unroll
    for (int off = 1; off < 64; off <<= 1) {
      float ov = __shfl_xor(best, off, 64);
      int oi = __shfl_xor(bidx, off, 64);
      if (ov > best || (ov == best && oi < bidx)) { best = ov; bidx = oi; }
    }
    if (lane == 0) { wbv[wvi] = best; wbi[wvi] = bidx; }
    __syncthreads();
    if (tid == 0) {
      float bb = wbv[0]; int bi2 = wbi[0];
#pragma unroll
      for (int w = 1; w < 4; ++w)
        if (wbv[w] > bb || (wbv[w] == bb && wbi[w] < bi2)) { bb = wbv[w]; bi2 = wbi[w]; }
      topv[b * NKC + it] = bb;
      topi[b * NKC + it] = bi2;
      gbv = bb; gbi = bi2;
    }
    __syncthreads();
    int gi = gbi;
    if ((gi >> 4) == tid) v[gi & 15] = -1e30f;
  }
}

// ---------------------------------------------------------------------------
// K5: roi generation
// ---------------------------------------------------------------------------
__global__ __launch_bounds__(256) void rois_k(const float* __restrict__ topv,
    const int* __restrict__ topi, int* __restrict__ idxb, float* __restrict__ rmask,
    float* __restrict__ rel, float* __restrict__ out_rois, float* __restrict__ out_act)
{
  int t = blockIdx.x * 256 + threadIdx.x;
  if (t >= NROI) return;
  int b = t >> 8, k = t & 255, kc = k >> 2, ns = k & 3;
  float tv = topv[b * NKC + kc];
  float c = (float)topi[b * NKC + kc];
  const float scales[4] = {16.f, 64.f, 128.f, 256.f};
  float half = scales[ns] * 0.5f;
  float s = fminf(fmaxf(c - half, 0.f), 4095.f);
  float e = fminf(fmaxf(c + half, 1.f), 4096.f);
  e = fmaxf(e, s + 1.f);
  float L = e - s;
  float ss = fminf(fmaxf(s - L * 0.25f, 0.f), 4095.f);
  float se = s + L * 0.25f;
  float es = e - L * 0.25f;
  float ee = fminf(fmaxf(e + L * 0.25f, 1.f), 4096.f);
  float st[3] = {ss, s, es};
  float en[3] = {se, e, ee};
#pragma unroll
  for (int r = 0; r < 3; ++r)
#pragma unroll
    for (int p = 0; p < 4; ++p) {
      float frac = ((float)p + 0.5f) * 0.25f;
      float fidx = floorf(st[r] + (en[r] - st[r]) * frac);
      fidx = fminf(fmaxf(fidx, 0.f), 4095.f);
      idxb[t * 12 + r * 4 + p] = (int)fidx;
    }
  rmask[t] = (tv > 0.5f) ? 1.f : 0.f;
  rel[t * 2 + 0] = s * (1.f / 4096.f);
  rel[t * 2 + 1] = e * (1.f / 4096.f);
  out_rois[t * 2 + 0] = s;
  out_rois[t * 2 + 1] = e;
  out_act[t] = tv;
}

// ---------------------------------------------------------------------------
// K6: x0 = gathered-pool GEMM + bias + pos_emb (r9 plain single-buffer)
// ---------------------------------------------------------------------------
__global__ __launch_bounds__(256) void pool_gemm_k(const float* __restrict__ enc,
    const int* __restrict__ idxb, const float* __restrict__ Wp,
    const float* __restrict__ bp, const float* __restrict__ rel,
    float* __restrict__ x0)
{
  __shared__ float As[16][66];
  __shared__ float Ws[16][68];
  int tid = threadIdx.x;
  int tx = tid & 15, ty = tid >> 4;
  int m0 = blockIdx.x * 64, n0 = blockIdx.y * 64;
  int lr = tid >> 2, lc = tid & 3;
  int wr = tid >> 4, wc = tid & 15;
  int roi = m0 + lr;
  int b = roi >> 8;
  float acc[4][4] = {};
  for (int kk = 0; kk < 3072; kk += 16) {
    int slot = kk >> 8, kd = kk & 255;
    int trow = idxb[roi * 12 + slot];
    float4 av = *reinterpret_cast<const float4*>(
        enc + ((size_t)(b * NT + trow)) * 256 + kd + lc * 4);
    As[lc * 4 + 0][lr] = av.x;
    As[lc * 4 + 1][lr] = av.y;
    As[lc * 4 + 2][lr] = av.z;
    As[lc * 4 + 3][lr] = av.w;
    float4 wv = *reinterpret_cast<const float4*>(Wp + (size_t)(kk + wr) * 256 + n0 + wc * 4);
    *reinterpret_cast<float4*>(&Ws[wr][wc * 4]) = wv;
    __syncthreads();
#pragma unroll
    for (int k = 0; k < 16; ++k) {
      float4 a4 = *reinterpret_cast<const float4*>(&As[k][ty * 4]);
      float4 b4 = *reinterpret_cast<const float4*>(&Ws[k][tx * 4]);
      float aa[4] = {a4.x, a4.y, a4.z, a4.w};
      float bb[4] = {b4.x, b4.y, b4.z, b4.w};
#pragma unroll
      for (int i = 0; i < 4; ++i)
#pragma unroll
        for (int j = 0; j < 4; ++j)
          acc[i][j] += aa[i] * bb[j];
    }
    __syncthreads();
  }
#pragma unroll
  for (int i = 0; i < 4; ++i) {
    int rr = m0 + ty * 4 + i;
    float r0 = rel[rr * 2], r1 = rel[rr * 2 + 1];
    float o[4];
#pragma unroll
    for (int j = 0; j < 4; ++j) {
      int col = n0 + tx * 4 + j;
      int rsel = col >> 7, cc = col & 127, j2 = cc & 63;
      float freq = expf(-0.14391156831212787f * (float)j2);  // ln(10000)/64
      float ang = ((rsel == 0) ? r0 : r1) * freq;
      float pe = (cc < 64) ? sinf(ang) : cosf(ang);
      o[j] = acc[i][j] + bp[col] + pe;
    }
    *reinterpret_cast<float4*>(x0 + (size_t)rr * 256 + n0 + tx * 4) =
        make_float4(o[0], o[1], o[2], o[3]);
  }
}

// ---------------------------------------------------------------------------
// K8: attention per (b,h). qkv packed [2048][768]: q=0.., k=256.., v=512..
// One-pass online softmax (round-10 tail win).
// ---------------------------------------------------------------------------
__global__ __launch_bounds__(256) void attn_k(const float* __restrict__ qkv,
    const float* __restrict__ rmask, float* __restrict__ ctx)
{
  __shared__ float ks[256][32];
  __shared__ float vs[256][32];
  int bh = blockIdx.x;
  int b = bh >> 3, h = bh & 7;
  int tid = threadIdx.x;
  size_t rowb = (size_t)b * 256;
  for (int idx = tid; idx < 2048; idx += 256) {
    int r = idx >> 3, dg = idx & 7;
    *reinterpret_cast<float4*>(&ks[r][dg * 4]) =
        *reinterpret_cast<const float4*>(qkv + (rowb + r) * 768 + 256 + h * 32 + dg * 4);
    *reinterpret_cast<float4*>(&vs[r][dg * 4]) =
        *reinterpret_cast<const float4*>(qkv + (rowb + r) * 768 + 512 + h * 32 + dg * 4);
  }
  __syncthreads();
  float qr[32];
#pragma unroll
  for (int dg = 0; dg < 8; ++dg)
    *reinterpret_cast<float4*>(&qr[dg * 4]) =
        *reinterpret_cast<const float4*>(qkv + (rowb + tid) * 768 + h * 32 + dg * 4);
  const float invs = 0.17677669529663689f;  // 1/sqrt(32)
  float m = -1e30f, l = 0.f;
  float accd[32] = {};
  for (int kk = 0; kk < 256; ++kk) {
    float s = 0.f;
#pragma unroll
    for (int d = 0; d < 32; ++d) s += qr[d] * ks[kk][d];
    s = s * invs + (1.f - rmask[b * 256 + kk]) * -1e9f;
    if (s > m) {
      float corr = expf(m - s);
      l *= corr;
#pragma unroll
      for (int d = 0; d < 32; ++d) accd[d] *= corr;
      m = s;
    }
    float p = expf(s - m);
    l += p;
#pragma unroll
    for (int d = 0; d < 32; ++d) accd[d] += p * vs[kk][d];
  }
  float inv = 1.f / l;
#pragma unroll
  for (int dg = 0; dg < 8; ++dg) {
    float4 o = make_float4(accd[dg * 4] * inv, accd[dg * 4 + 1] * inv,
                           accd[dg * 4 + 2] * inv, accd[dg * 4 + 3] * inv);
    *reinterpret_cast<float4*>(ctx + (rowb + tid) * 256 + h * 32 + dg * 4) = o;
  }
}

// ---------------------------------------------------------------------------
// K9: in-place LayerNorm over last dim (256). One wave64 per row, 4 rows/block.
// ---------------------------------------------------------------------------
__global__ __launch_bounds__(256) void ln_k(float* __restrict__ x,
    const float* __restrict__ g, const float* __restrict__ bb)
{
  int row = blockIdx.x * 4 + (threadIdx.x >> 6);
  int lane = threadIdx.x & 63;
  float* xr = x + (size_t)row * 256;
  float4 v = *reinterpret_cast<const float4*>(xr + lane * 4);
  float s = v.x + v.y + v.z + v.w;
#pragma unroll
  for (int off = 32; off > 0; off >>= 1) s += __shfl_xor(s, off, 64);
  float mean = s * 0.00390625f;
  float dx[4] = {v.x - mean, v.y - mean, v.z - mean, v.w - mean};
  float s2 = dx[0] * dx[0] + dx[1] * dx[1] + dx[2] * dx[2] + dx[3] * dx[3];
#pragma unroll
  for (int off = 32; off > 0; off >>= 1) s2 += __shfl_xor(s2, off, 64);
  float var = s2 * 0.00390625f;
  float rs = 1.f / sqrtf(var + 1e-6f);
  int c = lane * 4;
  float4 o;
  o.x = dx[0] * rs * g[c + 0] + bb[c + 0];
  o.y = dx[1] * rs * g[c + 1] + bb[c + 1];
  o.z = dx[2] * rs * g[c + 2] + bb[c + 2];
  o.w = dx[3] * rs * g[c + 3] + bb[c + 3];
  *reinterpret_cast<float4*>(xr + lane * 4) = o;
}

// ---------------------------------------------------------------------------
// K12: classifier + 2-way softmax. One wave64 per row, shuffle reduce.
// ---------------------------------------------------------------------------
__global__ __launch_bounds__(256) void cls_k(const float* __restrict__ x2,
    const float* __restrict__ Wc, const float* __restrict__ bc,
    float* __restrict__ out)
{
  int row = blockIdx.x * 4 + (threadIdx.x >> 6);
  int lane = threadIdx.x & 63;
  const float* xr = x2 + (size_t)row * 256;
  float4 xv = *reinterpret_cast<const float4*>(xr + lane * 4);
  int c = lane * 4;
  float4 w01 = *reinterpret_cast<const float4*>(Wc + c * 2);       // Wc[c..c+1][0..1]
  float4 w23 = *reinterpret_cast<const float4*>(Wc + c * 2 + 4);   // Wc[c+2..c+3][0..1]
  float l0 = xv.x * w01.x + xv.y * w01.z + xv.z * w23.x + xv.w * w23.z;
  float l1 = xv.x * w01.y + xv.y * w01.w + xv.z * w23.y + xv.w * w23.w;
#pragma unroll
  for (int off = 32; off > 0; off >>= 1) {
    l0 += __shfl_xor(l0, off, 64);
    l1 += __shfl_xor(l1, off, 64);
  }
  if (lane == 0) {
    l0 += bc[0]; l1 += bc[1];
    float mm = fmaxf(l0, l1);
    float e0 = expf(l0 - mm), e1 = expf(l1 - mm);
    float inv = 1.f / (e0 + e1);
    out[row * 2 + 0] = e0 * inv;
    out[row * 2 + 1] = e1 * inv;
  }
}

// ---------------------------------------------------------------------------
extern "C" void kernel_launch(void* const* d_in, const int* in_sizes, int n_in,
                              void* d_out, int out_size, void* d_ws, size_t ws_size,
                              hipStream_t stream) {
  (void)in_sizes; (void)n_in; (void)out_size; (void)ws_size;
  const float* feature = (const float*)d_in[0];
  const float* fmask   = (const float*)d_in[2];
  const float* W_red   = (const float*)d_in[3];
  const float* b_red   = (const float*)d_in[4];
  const float* conv1_w = (const float*)d_in[5];
  const float* conv1_b = (const float*)d_in[6];
  const float* conv2_w = (const float*)d_in[7];
  const float* conv2_b = (const float*)d_in[8];
  const float* W_sc    = (const float*)d_in[9];
  const float* b_sc    = (const float*)d_in[10];
  const float* W_pool  = (const float*)d_in[11];
  const float* b_pool  = (const float*)d_in[12];
  const float* Wq      = (const float*)d_in[13];
  const float* Wk      = (const float*)d_in[14];
  const float* Wv      = (const float*)d_in[15];
  const float* Wo      = (const float*)d_in[16];
  const float* ln1_g   = (const float*)d_in[17];
  const float* ln1_b   = (const float*)d_in[18];
  const float* W1      = (const float*)d_in[19];
  const float* b1      = (const float*)d_in[20];
  const float* W2      = (const float*)d_in[21];
  const float* b2      = (const float*)d_in[22];
  const float* ln2_g   = (const float*)d_in[23];
  const float* ln2_b   = (const float*)d_in[24];
  const float* W_cls   = (const float*)d_in[25];
  const float* b_cls   = (const float*)d_in[26];

  float* ws = (float*)d_ws;
  float* enc   = ws;                       // 8388608 floats (32768x256)
  float* h1    = ws + 8388608;             // 8388608 floats
  float* Wt1   = ws + 16777216;            // 196608
  float* Wt2   = ws + 16973824;            // 196608
  float* act   = ws + 17170432;            // 32768
  float* topv  = ws + 17203200;            // 512
  int*   topi  = (int*)(ws + 17203712);    // 512
  int*   idxb  = (int*)(ws + 17204224);    // 24576
  float* rmask = ws + 17228800;            // 2048
  float* rel   = ws + 17230848;            // 4096
  float* pscore = ws + 17234944;           // 65536 (32768x2)
  // attention-phase buffers overlay the (freed after conv2) h1 region
  float* x0   = h1;                        // 524288
  float* qkv  = h1 + 524288;               // 1572864 (2048x768)
  float* ctx  = h1 + 2097152;              // 524288
  float* x1   = h1 + 2621440;              // 524288
  float* ft   = h1 + 3145728;              // 2097152 (2048x1024)
  float* x2   = h1 + 5242880;              // 524288
  float* Wqkv = h1 + 5767168;              // 196608 (written after conv2 frees h1)

  float* orois  = (float*)d_out;           // [B,K,2] = 4096
  float* oact   = orois + 4096;            // [B,K]   = 2048
  float* oscore = orois + 6144;            // [B,K,2] = 4096

  transw_k<<<1536, 256, 0, stream>>>(conv1_w, conv2_w, Wt1, Wt2);
  gemm1_k<<<dim3(256, 2), 256, 0, stream>>>(feature, W_red, b_red, enc,
                                            NBT, NDIN, ND);
  conv_t<0><<<dim3(256, 2), 256, 0, stream>>>(enc, Wt1, conv1_b, h1, nullptr, nullptr);
  conv_t<1><<<dim3(256, 2), 256, 0, stream>>>(h1, Wt2, conv2_b, nullptr, W_sc, pscore);
  actness_k<<<128, 256, 0, stream>>>(pscore, b_sc, fmask, act);
  topk_k<<<NB, 256, 0, stream>>>(act, topv, topi);
  rois_k<<<NB, 256, 0, stream>>>(topv, topi, idxb, rmask, rel, orois, oact);
  concatw_k<<<768, 256, 0, stream>>>(Wq, Wk, Wv, Wqkv);   // h1 free after conv2
  pool_gemm_k<<<dim3(32, 4), 256, 0, stream>>>(enc, idxb, W_pool, b_pool, rel, x0);
  gemm_k<0><<<dim3(32, 12), 256, 0, stream>>>(x0, Wqkv, nullptr, nullptr, qkv,
                                              NROI, ND, 768);
  attn_k<<<NB * NH, 256, 0, stream>>>(qkv, rmask, ctx);
  gemm_k<0><<<dim3(32, 4), 256, 0, stream>>>(ctx, Wo, nullptr, x0, x1, NROI, ND, ND);
  ln_k<<<512, 256, 0, stream>>>(x1, ln1_g, ln1_b);
  gemm_k<2><<<dim3(32, 16), 256, 0, stream>>>(x1, W1, b1, nullptr, ft, NROI, ND, 1024);
  gemm_k<0><<<dim3(32, 4), 256, 0, stream>>>(ft, W2, b2, x1, x2, NROI, 1024, ND);
  ln_k<<<512, 256, 0, stream>>>(x2, ln2_g, ln2_b);
  cls_k<<<512, 256, 0, stream>>>(x2, W_cls, b_cls, oscore);
}

// Round 12
// 1051.882 us; speedup vs baseline: 1.1379x; 1.0115x over previous
//
#include <hip/hip_runtime.h>
#include <hip/hip_bf16.h>
#include <math.h>

// Problem constants
#define NB 8
#define NT 4096
#define NBT 32768      // NB*NT
#define NDIN 1024
#define ND 256
#define NH 8
#define NDK 32
#define NKC 64
#define NNS 4
#define NRK 256        // rois per batch
#define NROI 2048      // NB*NRK

#define F4Z make_float4(0.f, 0.f, 0.f, 0.f)

// ---------------------------------------------------------------------------
// K0: transpose conv weights  w[o][i][tap] -> Wt[(tap*256+i)][o]
// ---------------------------------------------------------------------------
__global__ __launch_bounds__(256) void transw_k(const float* __restrict__ w1,
    const float* __restrict__ w2, float* __restrict__ Wt1, float* __restrict__ Wt2)
{
  int i = blockIdx.x * 256 + threadIdx.x;          // < 2*196608
  const float* w = (i >= 196608) ? w2 : w1;
  float* Wt = (i >= 196608) ? Wt2 : Wt1;
  int j = (i >= 196608) ? (i - 196608) : i;
  int co = j & 255;
  int rest = j >> 8;
  int ci = rest & 255;
  int tap = rest >> 8;
  Wt[j] = w[(size_t)co * 768 + ci * 3 + tap];
}

// K0b: concat Wq|Wk|Wv -> Wqkv [256][768]
__global__ __launch_bounds__(256) void concatw_k(const float* __restrict__ Wq,
    const float* __restrict__ Wk, const float* __restrict__ Wv,
    float* __restrict__ Wqkv)
{
  int d = blockIdx.x * 256 + threadIdx.x;          // < 196608
  int r = d / 768, c = d % 768;
  int m = c >> 8, cc = c & 255;
  const float* src = (m == 0) ? Wq : (m == 1) ? Wk : Wv;
  Wqkv[d] = src[r * 256 + cc];
}

// ---------------------------------------------------------------------------
// K1: gemm1 (feature @ W_red, SELU). 128x128 tile, 512 threads, 8x4/thread,
// BK=16, single-buffer. 512thr => 16 waves/CU at 2 blocks/CU = 4 waves/SIMD
// (vs 2 with 256thr) — occupancy was grid-limited (round-11 counters).
// ---------------------------------------------------------------------------
__global__ __launch_bounds__(512) void gemm1_k(const float* __restrict__ A,
    const float* __restrict__ W, const float* __restrict__ bias,
    float* __restrict__ C, int M, int Ka, int N)
{
  __shared__ float As[16][132];   // k-major
  __shared__ float Ws[16][128];
  int tid = threadIdx.x;
  int tx = tid & 31, ty = tid >> 5;    // 32 col-groups x 16 row-groups
  int m0 = blockIdx.x * 128, n0 = blockIdx.y * 128;
  int ar = tid >> 2, acg = tid & 3;    // A staging: 128 rows x 4 cg -> 1/thread
  int wk = tid >> 5, wn = tid & 31;    // W staging: 16 k x 32 cg -> 1/thread
  float acc[8][4] = {};
  for (int kk = 0; kk < Ka; kk += 16) {
    float4 av = *reinterpret_cast<const float4*>(A + (size_t)(m0 + ar) * Ka + kk + acg * 4);
    As[acg * 4 + 0][ar] = av.x;
    As[acg * 4 + 1][ar] = av.y;
    As[acg * 4 + 2][ar] = av.z;
    As[acg * 4 + 3][ar] = av.w;
    *reinterpret_cast<float4*>(&Ws[wk][wn * 4]) =
        *reinterpret_cast<const float4*>(W + (size_t)(kk + wk) * N + n0 + wn * 4);
    __syncthreads();
#pragma unroll
    for (int k = 0; k < 16; ++k) {
      float4 xa = *reinterpret_cast<const float4*>(&As[k][ty * 4]);
      float4 xb = *reinterpret_cast<const float4*>(&As[k][64 + ty * 4]);
      float4 wa = *reinterpret_cast<const float4*>(&Ws[k][tx * 4]);
      float aa[8] = {xa.x, xa.y, xa.z, xa.w, xb.x, xb.y, xb.z, xb.w};
      float bb[4] = {wa.x, wa.y, wa.z, wa.w};
#pragma unroll
      for (int i = 0; i < 8; ++i)
#pragma unroll
        for (int j = 0; j < 4; ++j)
          acc[i][j] += aa[i] * bb[j];
    }
    __syncthreads();
  }
#pragma unroll
  for (int i = 0; i < 8; ++i) {
    int row = m0 + ((i < 4) ? (ty * 4 + i) : (64 + ty * 4 + (i - 4)));
    int col = n0 + tx * 4;
    float o[4];
#pragma unroll
    for (int j = 0; j < 4; ++j) {
      float v = acc[i][j] + bias[col + j];
      v = (v > 0.f) ? 1.0507009873554805f * v
                    : 1.0507009873554805f * 1.6732632423543772f * expm1f(v);
      o[j] = v;
    }
    *reinterpret_cast<float4*>(C + (size_t)row * N + col) =
        make_float4(o[0], o[1], o[2], o[3]);
  }
}

// ---------------------------------------------------------------------------
// K2/K3: conv AS A K=768 GEMM (A_eff[t][tap*256+i] = in[t-1+tap][i]).
// 512 threads, 128x128 tile, 8x4/thread. EPI=0: ReLU; EPI=1: score fused.
// ---------------------------------------------------------------------------
template<int EPI>
__global__ __launch_bounds__(512) void conv_t(const float* __restrict__ in,
    const float* __restrict__ Wt, const float* __restrict__ bias,
    float* __restrict__ out, const float* __restrict__ Wsc,
    float* __restrict__ pscore)
{
  __shared__ float As[16][132];
  __shared__ float Ws[16][128];
  int tid = threadIdx.x;
  int tx = tid & 31, ty = tid >> 5;
  int m0 = blockIdx.x * 128, n0 = blockIdx.y * 128;
  int bstart = m0 & ~(NT - 1);
  int ar = tid >> 2, acg = tid & 3;
  int wk = tid >> 5, wn = tid & 31;
  float acc[8][4] = {};
  for (int kk = 0; kk < 768; kk += 16) {
    int tap = kk >> 8, kd = kk & 255;
    int g = m0 - 1 + tap + ar;
    bool ok = (g >= bstart) && (g < bstart + NT);
    float4 av = ok ? *reinterpret_cast<const float4*>(in + (size_t)g * 256 + kd + acg * 4)
                   : F4Z;
    As[acg * 4 + 0][ar] = av.x;
    As[acg * 4 + 1][ar] = av.y;
    As[acg * 4 + 2][ar] = av.z;
    As[acg * 4 + 3][ar] = av.w;
    *reinterpret_cast<float4*>(&Ws[wk][wn * 4]) =
        *reinterpret_cast<const float4*>(Wt + (size_t)(kk + wk) * 256 + n0 + wn * 4);
    __syncthreads();
#pragma unroll
    for (int k = 0; k < 16; ++k) {
      float4 xa = *reinterpret_cast<const float4*>(&As[k][ty * 4]);
      float4 xb = *reinterpret_cast<const float4*>(&As[k][64 + ty * 4]);
      float4 wa = *reinterpret_cast<const float4*>(&Ws[k][tx * 4]);
      float aa[8] = {xa.x, xa.y, xa.z, xa.w, xb.x, xb.y, xb.z, xb.w};
      float bb[4] = {wa.x, wa.y, wa.z, wa.w};
#pragma unroll
      for (int i = 0; i < 8; ++i)
#pragma unroll
        for (int j = 0; j < 4; ++j)
          acc[i][j] += aa[i] * bb[j];
    }
    __syncthreads();
  }

  if (EPI == 0) {
#pragma unroll
    for (int i = 0; i < 8; ++i) {
      int row = m0 + ((i < 4) ? (ty * 4 + i) : (64 + ty * 4 + (i - 4)));
      int col = n0 + tx * 4;
      float o[4];
#pragma unroll
      for (int j = 0; j < 4; ++j)
        o[j] = fmaxf(acc[i][j] + bias[col + j], 0.f);
      *reinterpret_cast<float4*>(out + (size_t)row * 256 + col) =
          make_float4(o[0], o[1], o[2], o[3]);
    }
  } else {
    float p[8];
#pragma unroll
    for (int i = 0; i < 8; ++i) {
      float s = 0.f;
#pragma unroll
      for (int j = 0; j < 4; ++j) {
        int col = n0 + tx * 4 + j;
        float v = fmaxf(acc[i][j] + bias[col], 0.f);
        s += v * Wsc[col * 3];          // W_sc[col][0]
      }
      p[i] = s;
    }
    // reduce across tx (32 lanes; offsets<32 stay within the half-wave)
#pragma unroll
    for (int off = 1; off < 32; off <<= 1)
#pragma unroll
      for (int i = 0; i < 8; ++i)
        p[i] += __shfl_xor(p[i], off, 64);
    if (tx == 0) {
#pragma unroll
      for (int i = 0; i < 8; ++i) {
        int row = m0 + ((i < 4) ? (ty * 4 + i) : (64 + ty * 4 + (i - 4)));
        pscore[(size_t)row * 2 + blockIdx.y] = p[i];
      }
    }
  }
}

// K3b: actness[g] = sigmoid(sum pscore[g][:] + b_sc0) * mask[g]
__global__ __launch_bounds__(256) void actness_k(const float* __restrict__ pscore,
    const float* __restrict__ bsc, const float* __restrict__ fmask,
    float* __restrict__ actness)
{
  int g = blockIdx.x * 256 + threadIdx.x;
  float2 pv = *reinterpret_cast<const float2*>(pscore + (size_t)g * 2);
  float z = pv.x + pv.y + bsc[0];
  actness[g] = (1.f / (1.f + expf(-z))) * fmask[g];
}

// ---------------------------------------------------------------------------
// Generic tiled fp32 GEMM (small shapes): 64x64 tile, 4x4/thread (r9 plain).
// ---------------------------------------------------------------------------
template<int ACT>
__global__ __launch_bounds__(256) void gemm_k(const float* __restrict__ A,
    const float* __restrict__ W, const float* __restrict__ bias,
    const float* __restrict__ resid, float* __restrict__ C,
    int M, int Ka, int N)
{
  __shared__ float As[16][66];
  __shared__ float Ws[16][68];
  int tid = threadIdx.x;
  int tx = tid & 15, ty = tid >> 4;
  int m0 = blockIdx.x * 64, n0 = blockIdx.y * 64;
  int lr = tid >> 2, lc = tid & 3;     // A-load: row, col-group
  int wr = tid >> 4, wc = tid & 15;    // W-load: row, col-group
  float acc[4][4] = {};
  for (int kk = 0; kk < Ka; kk += 16) {
    float4 av = *reinterpret_cast<const float4*>(A + (size_t)(m0 + lr) * Ka + kk + lc * 4);
    As[lc * 4 + 0][lr] = av.x;
    As[lc * 4 + 1][lr] = av.y;
    As[lc * 4 + 2][lr] = av.z;
    As[lc * 4 + 3][lr] = av.w;
    float4 wv = *reinterpret_cast<const float4*>(W + (size_t)(kk + wr) * N + n0 + wc * 4);
    *reinterpret_cast<float4*>(&Ws[wr][wc * 4]) = wv;
    __syncthreads();
#pragma unroll
    for (int k = 0; k < 16; ++k) {
      float4 a4 = *reinterpret_cast<const float4*>(&As[k][ty * 4]);
      float4 b4 = *reinterpret_cast<const float4*>(&Ws[k][tx * 4]);
      float aa[4] = {a4.x, a4.y, a4.z, a4.w};
      float bb[4] = {b4.x, b4.y, b4.z, b4.w};
#pragma unroll
      for (int i = 0; i < 4; ++i)
#pragma unroll
        for (int j = 0; j < 4; ++j)
          acc[i][j] += aa[i] * bb[j];
    }
    __syncthreads();
  }
#pragma unroll
  for (int i = 0; i < 4; ++i) {
    int row = m0 + ty * 4 + i;
    float o[4];
#pragma unroll
    for (int j = 0; j < 4; ++j) {
      int col = n0 + tx * 4 + j;
      float v = acc[i][j];
      if (bias) v += bias[col];
      if (resid) v += resid[(size_t)row * N + col];
      if (ACT == 1) {
        v = (v > 0.f) ? 1.0507009873554805f * v
                      : 1.0507009873554805f * 1.6732632423543772f * expm1f(v);
      } else if (ACT == 2) {
        v = fmaxf(v, 0.f);
      }
      o[j] = v;
    }
    *reinterpret_cast<float4*>(C + (size_t)row * N + n0 + tx * 4) =
        make_float4(o[0], o[1], o[2], o[3]);
  }
}

// ---------------------------------------------------------------------------
// K4: per-batch exact top-64 (lax.top_k semantics: sorted desc, ties -> lower idx)
// ---------------------------------------------------------------------------
__global__ __launch_bounds__(256) void topk_k(const float* __restrict__ actness,
    float* __restrict__ topv, int* __restrict__ topi)
{
  __shared__ float wbv[4];
  __shared__ int wbi[4];
  __shared__ float gbv;
  __shared__ int gbi;
  int b = blockIdx.x;
  int tid = threadIdx.x;
  int lane = tid & 63, wvi = tid >> 6;
  float v[16];
  const float* src = actness + (size_t)b * NT + tid * 16;
#pragma unroll
  for (int j = 0; j < 16; j += 4)
    *reinterpret_cast<float4*>(&v[j]) = *reinterpret_cast<const float4*>(src + j);
  for (int it = 0; it < NKC; ++it) {
    float best = -1e30f; int bj = 0;
#pragma unroll
    for (int j = 0; j < 16; ++j)
      if (v[j] > best) { best = v[j]; bj = j; }   // first max -> lowest local idx
    int bidx = tid * 16 + bj;
#pragma unroll
    for (int off = 1; off < 64; off <<= 1) {
      float ov = __shfl_xor(best, off, 64);
      int oi = __shfl_xor(bidx, off, 64);
      if (ov > best || (ov == best && oi < bidx)) { best = ov; bidx = oi; }
    }
    if (lane == 0) { wbv[wvi] = best; wbi[wvi] = bidx; }
    __syncthreads();
    if (tid == 0) {
      float bb = wbv[0]; int bi2 = wbi[0];
#pragma unroll
      for (int w = 1; w < 4; ++w)
        if (wbv[w] > bb || (wbv[w] == bb && wbi[w] < bi2)) { bb = wbv[w]; bi2 = wbi[w]; }
      topv[b * NKC + it] = bb;
      topi[b * NKC + it] = bi2;
      gbv = bb; gbi = bi2;
    }
    __syncthreads();
    int gi = gbi;
    if ((gi >> 4) == tid) v[gi & 15] = -1e30f;
  }
}

// ---------------------------------------------------------------------------
// K5: roi generation
// ---------------------------------------------------------------------------
__global__ __launch_bounds__(256) void rois_k(const float* __restrict__ topv,
    const int* __restrict__ topi, int* __restrict__ idxb, float* __restrict__ rmask,
    float* __restrict__ rel, float* __restrict__ out_rois, float* __restrict__ out_act)
{
  int t = blockIdx.x * 256 + threadIdx.x;
  if (t >= NROI) return;
  int b = t >> 8, k = t & 255, kc = k >> 2, ns = k & 3;
  float tv = topv[b * NKC + kc];
  float c = (float)topi[b * NKC + kc];
  const float scales[4] = {16.f, 64.f, 128.f, 256.f};
  float half = scales[ns] * 0.5f;
  float s = fminf(fmaxf(c - half, 0.f), 4095.f);
  float e = fminf(fmaxf(c + half, 1.f), 4096.f);
  e = fmaxf(e, s + 1.f);
  float L = e - s;
  float ss = fminf(fmaxf(s - L * 0.25f, 0.f), 4095.f);
  float se = s + L * 0.25f;
  float es = e - L * 0.25f;
  float ee = fminf(fmaxf(e + L * 0.25f, 1.f), 4096.f);
  float st[3] = {ss, s, es};
  float en[3] = {se, e, ee};
#pragma unroll
  for (int r = 0; r < 3; ++r)
#pragma unroll
    for (int p = 0; p < 4; ++p) {
      float frac = ((float)p + 0.5f) * 0.25f;
      float fidx = floorf(st[r] + (en[r] - st[r]) * frac);
      fidx = fminf(fmaxf(fidx, 0.f), 4095.f);
      idxb[t * 12 + r * 4 + p] = (int)fidx;
    }
  rmask[t] = (tv > 0.5f) ? 1.f : 0.f;
  rel[t * 2 + 0] = s * (1.f / 4096.f);
  rel[t * 2 + 1] = e * (1.f / 4096.f);
  out_rois[t * 2 + 0] = s;
  out_rois[t * 2 + 1] = e;
  out_act[t] = tv;
}

// ---------------------------------------------------------------------------
// K6: x0 = gathered-pool GEMM + bias + pos_emb (r9 plain single-buffer)
// ---------------------------------------------------------------------------
__global__ __launch_bounds__(256) void pool_gemm_k(const float* __restrict__ enc,
    const int* __restrict__ idxb, const float* __restrict__ Wp,
    const float* __restrict__ bp, const float* __restrict__ rel,
    float* __restrict__ x0)
{
  __shared__ float As[16][66];
  __shared__ float Ws[16][68];
  int tid = threadIdx.x;
  int tx = tid & 15, ty = tid >> 4;
  int m0 = blockIdx.x * 64, n0 = blockIdx.y * 64;
  int lr = tid >> 2, lc = tid & 3;
  int wr = tid >> 4, wc = tid & 15;
  int roi = m0 + lr;
  int b = roi >> 8;
  float acc[4][4] = {};
  for (int kk = 0; kk < 3072; kk += 16) {
    int slot = kk >> 8, kd = kk & 255;
    int trow = idxb[roi * 12 + slot];
    float4 av = *reinterpret_cast<const float4*>(
        enc + ((size_t)(b * NT + trow)) * 256 + kd + lc * 4);
    As[lc * 4 + 0][lr] = av.x;
    As[lc * 4 + 1][lr] = av.y;
    As[lc * 4 + 2][lr] = av.z;
    As[lc * 4 + 3][lr] = av.w;
    float4 wv = *reinterpret_cast<const float4*>(Wp + (size_t)(kk + wr) * 256 + n0 + wc * 4);
    *reinterpret_cast<float4*>(&Ws[wr][wc * 4]) = wv;
    __syncthreads();
#pragma unroll
    for (int k = 0; k < 16; ++k) {
      float4 a4 = *reinterpret_cast<const float4*>(&As[k][ty * 4]);
      float4 b4 = *reinterpret_cast<const float4*>(&Ws[k][tx * 4]);
      float aa[4] = {a4.x, a4.y, a4.z, a4.w};
      float bb[4] = {b4.x, b4.y, b4.z, b4.w};
#pragma unroll
      for (int i = 0; i < 4; ++i)
#pragma unroll
        for (int j = 0; j < 4; ++j)
          acc[i][j] += aa[i] * bb[j];
    }
    __syncthreads();
  }
#pragma unroll
  for (int i = 0; i < 4; ++i) {
    int rr = m0 + ty * 4 + i;
    float r0 = rel[rr * 2], r1 = rel[rr * 2 + 1];
    float o[4];
#pragma unroll
    for (int j = 0; j < 4; ++j) {
      int col = n0 + tx * 4 + j;
      int rsel = col >> 7, cc = col & 127, j2 = cc & 63;
      float freq = expf(-0.14391156831212787f * (float)j2);  // ln(10000)/64
      float ang = ((rsel == 0) ? r0 : r1) * freq;
      float pe = (cc < 64) ? sinf(ang) : cosf(ang);
      o[j] = acc[i][j] + bp[col] + pe;
    }
    *reinterpret_cast<float4*>(x0 + (size_t)rr * 256 + n0 + tx * 4) =
        make_float4(o[0], o[1], o[2], o[3]);
  }
}

// ---------------------------------------------------------------------------
// K8: attention per (b,h). qkv packed [2048][768]: q=0.., k=256.., v=512..
// One-pass online softmax.
// ---------------------------------------------------------------------------
__global__ __launch_bounds__(256) void attn_k(const float* __restrict__ qkv,
    const float* __restrict__ rmask, float* __restrict__ ctx)
{
  __shared__ float ks[256][32];
  __shared__ float vs[256][32];
  int bh = blockIdx.x;
  int b = bh >> 3, h = bh & 7;
  int tid = threadIdx.x;
  size_t rowb = (size_t)b * 256;
  for (int idx = tid; idx < 2048; idx += 256) {
    int r = idx >> 3, dg = idx & 7;
    *reinterpret_cast<float4*>(&ks[r][dg * 4]) =
        *reinterpret_cast<const float4*>(qkv + (rowb + r) * 768 + 256 + h * 32 + dg * 4);
    *reinterpret_cast<float4*>(&vs[r][dg * 4]) =
        *reinterpret_cast<const float4*>(qkv + (rowb + r) * 768 + 512 + h * 32 + dg * 4);
  }
  __syncthreads();
  float qr[32];
#pragma unroll
  for (int dg = 0; dg < 8; ++dg)
    *reinterpret_cast<float4*>(&qr[dg * 4]) =
        *reinterpret_cast<const float4*>(qkv + (rowb + tid) * 768 + h * 32 + dg * 4);
  const float invs = 0.17677669529663689f;  // 1/sqrt(32)
  float m = -1e30f, l = 0.f;
  float accd[32] = {};
  for (int kk = 0; kk < 256; ++kk) {
    float s = 0.f;
#pragma unroll
    for (int d = 0; d < 32; ++d) s += qr[d] * ks[kk][d];
    s = s * invs + (1.f - rmask[b * 256 + kk]) * -1e9f;
    if (s > m) {
      float corr = expf(m - s);
      l *= corr;
#pragma unroll
      for (int d = 0; d < 32; ++d) accd[d] *= corr;
      m = s;
    }
    float p = expf(s - m);
    l += p;
#pragma unroll
    for (int d = 0; d < 32; ++d) accd[d] += p * vs[kk][d];
  }
  float inv = 1.f / l;
#pragma unroll
  for (int dg = 0; dg < 8; ++dg) {
    float4 o = make_float4(accd[dg * 4] * inv, accd[dg * 4 + 1] * inv,
                           accd[dg * 4 + 2] * inv, accd[dg * 4 + 3] * inv);
    *reinterpret_cast<float4*>(ctx + (rowb + tid) * 256 + h * 32 + dg * 4) = o;
  }
}

// ---------------------------------------------------------------------------
// K9: in-place LayerNorm over last dim (256). One wave64 per row, 4 rows/block.
// ---------------------------------------------------------------------------
__global__ __launch_bounds__(256) void ln_k(float* __restrict__ x,
    const float* __restrict__ g, const float* __restrict__ bb)
{
  int row = blockIdx.x * 4 + (threadIdx.x >> 6);
  int lane = threadIdx.x & 63;
  float* xr = x + (size_t)row * 256;
  float4 v = *reinterpret_cast<const float4*>(xr + lane * 4);
  float s = v.x + v.y + v.z + v.w;
#pragma unroll
  for (int off = 32; off > 0; off >>= 1) s += __shfl_xor(s, off, 64);
  float mean = s * 0.00390625f;
  float dx[4] = {v.x - mean, v.y - mean, v.z - mean, v.w - mean};
  float s2 = dx[0] * dx[0] + dx[1] * dx[1] + dx[2] * dx[2] + dx[3] * dx[3];
#pragma unroll
  for (int off = 32; off > 0; off >>= 1) s2 += __shfl_xor(s2, off, 64);
  float var = s2 * 0.00390625f;
  float rs = 1.f / sqrtf(var + 1e-6f);
  int c = lane * 4;
  float4 o;
  o.x = dx[0] * rs * g[c + 0] + bb[c + 0];
  o.y = dx[1] * rs * g[c + 1] + bb[c + 1];
  o.z = dx[2] * rs * g[c + 2] + bb[c + 2];
  o.w = dx[3] * rs * g[c + 3] + bb[c + 3];
  *reinterpret_cast<float4*>(xr + lane * 4) = o;
}

// ---------------------------------------------------------------------------
// K12: classifier + 2-way softmax. One wave64 per row, shuffle reduce.
// ---------------------------------------------------------------------------
__global__ __launch_bounds__(256) void cls_k(const float* __restrict__ x2,
    const float* __restrict__ Wc, const float* __restrict__ bc,
    float* __restrict__ out)
{
  int row = blockIdx.x * 4 + (threadIdx.x >> 6);
  int lane = threadIdx.x & 63;
  const float* xr = x2 + (size_t)row * 256;
  float4 xv = *reinterpret_cast<const float4*>(xr + lane * 4);
  int c = lane * 4;
  float4 w01 = *reinterpret_cast<const float4*>(Wc + c * 2);       // Wc[c..c+1][0..1]
  float4 w23 = *reinterpret_cast<const float4*>(Wc + c * 2 + 4);   // Wc[c+2..c+3][0..1]
  float l0 = xv.x * w01.x + xv.y * w01.z + xv.z * w23.x + xv.w * w23.z;
  float l1 = xv.x * w01.y + xv.y * w01.w + xv.z * w23.y + xv.w * w23.w;
#pragma unroll
  for (int off = 32; off > 0; off >>= 1) {
    l0 += __shfl_xor(l0, off, 64);
    l1 += __shfl_xor(l1, off, 64);
  }
  if (lane == 0) {
    l0 += bc[0]; l1 += bc[1];
    float mm = fmaxf(l0, l1);
    float e0 = expf(l0 - mm), e1 = expf(l1 - mm);
    float inv = 1.f / (e0 + e1);
    out[row * 2 + 0] = e0 * inv;
    out[row * 2 + 1] = e1 * inv;
  }
}

// ---------------------------------------------------------------------------
extern "C" void kernel_launch(void* const* d_in, const int* in_sizes, int n_in,
                              void* d_out, int out_size, void* d_ws, size_t ws_size,
                              hipStream_t stream) {
  (void)in_sizes; (void)n_in; (void)out_size; (void)ws_size;
  const float* feature = (const float*)d_in[0];
  const float* fmask   = (const float*)d_in[2];
  const float* W_red   = (const float*)d_in[3];
  const float* b_red   = (const float*)d_in[4];
  const float* conv1_w = (const float*)d_in[5];
  const float* conv1_b = (const float*)d_in[6];
  const float* conv2_w = (const float*)d_in[7];
  const float* conv2_b = (const float*)d_in[8];
  const float* W_sc    = (const float*)d_in[9];
  const float* b_sc    = (const float*)d_in[10];
  const float* W_pool  = (const float*)d_in[11];
  const float* b_pool  = (const float*)d_in[12];
  const float* Wq      = (const float*)d_in[13];
  const float* Wk      = (const float*)d_in[14];
  const float* Wv      = (const float*)d_in[15];
  const float* Wo      = (const float*)d_in[16];
  const float* ln1_g   = (const float*)d_in[17];
  const float* ln1_b   = (const float*)d_in[18];
  const float* W1      = (const float*)d_in[19];
  const float* b1      = (const float*)d_in[20];
  const float* W2      = (const float*)d_in[21];
  const float* b2      = (const float*)d_in[22];
  const float* ln2_g   = (const float*)d_in[23];
  const float* ln2_b   = (const float*)d_in[24];
  const float* W_cls   = (const float*)d_in[25];
  const float* b_cls   = (const float*)d_in[26];

  float* ws = (float*)d_ws;
  float* enc   = ws;                       // 8388608 floats (32768x256)
  float* h1    = ws + 8388608;             // 8388608 floats
  float* Wt1   = ws + 16777216;            // 196608
  float* Wt2   = ws + 16973824;            // 196608
  float* act   = ws + 17170432;            // 32768
  float* topv  = ws + 17203200;            // 512
  int*   topi  = (int*)(ws + 17203712);    // 512
  int*   idxb  = (int*)(ws + 17204224);    // 24576
  float* rmask = ws + 17228800;            // 2048
  float* rel   = ws + 17230848;            // 4096
  float* pscore = ws + 17234944;           // 65536 (32768x2)
  // attention-phase buffers overlay the (freed after conv2) h1 region
  float* x0   = h1;                        // 524288
  float* qkv  = h1 + 524288;               // 1572864 (2048x768)
  float* ctx  = h1 + 2097152;              // 524288
  float* x1   = h1 + 2621440;              // 524288
  float* ft   = h1 + 3145728;              // 2097152 (2048x1024)
  float* x2   = h1 + 5242880;              // 524288
  float* Wqkv = h1 + 5767168;              // 196608 (written after conv2 frees h1)

  float* orois  = (float*)d_out;           // [B,K,2] = 4096
  float* oact   = orois + 4096;            // [B,K]   = 2048
  float* oscore = orois + 6144;            // [B,K,2] = 4096

  transw_k<<<1536, 256, 0, stream>>>(conv1_w, conv2_w, Wt1, Wt2);
  gemm1_k<<<dim3(256, 2), 512, 0, stream>>>(feature, W_red, b_red, enc,
                                            NBT, NDIN, ND);
  conv_t<0><<<dim3(256, 2), 512, 0, stream>>>(enc, Wt1, conv1_b, h1, nullptr, nullptr);
  conv_t<1><<<dim3(256, 2), 512, 0, stream>>>(h1, Wt2, conv2_b, nullptr, W_sc, pscore);
  actness_k<<<128, 256, 0, stream>>>(pscore, b_sc, fmask, act);
  topk_k<<<NB, 256, 0, stream>>>(act, topv, topi);
  rois_k<<<NB, 256, 0, stream>>>(topv, topi, idxb, rmask, rel, orois, oact);
  concatw_k<<<768, 256, 0, stream>>>(Wq, Wk, Wv, Wqkv);   // h1 free after conv2
  pool_gemm_k<<<dim3(32, 4), 256, 0, stream>>>(enc, idxb, W_pool, b_pool, rel, x0);
  gemm_k<0><<<dim3(32, 12), 256, 0, stream>>>(x0, Wqkv, nullptr, nullptr, qkv,
                                              NROI, ND, 768);
  attn_k<<<NB * NH, 256, 0, stream>>>(qkv, rmask, ctx);
  gemm_k<0><<<dim3(32, 4), 256, 0, stream>>>(ctx, Wo, nullptr, x0, x1, NROI, ND, ND);
  ln_k<<<512, 256, 0, stream>>>(x1, ln1_g, ln1_b);
  gemm_k<2><<<dim3(32, 16), 256, 0, stream>>>(x1, W1, b1, nullptr, ft, NROI, ND, 1024);
  gemm_k<0><<<dim3(32, 4), 256, 0, stream>>>(ft, W2, b2, x1, x2, NROI, 1024, ND);
  ln_k<<<512, 256, 0, stream>>>(x2, ln2_g, ln2_b);
  cls_k<<<512, 256, 0, stream>>>(x2, W_cls, b_cls, oscore);
}